// Round 15
// baseline (4272.586 us; speedup 1.0000x reference)
//
#include <hip/hip_runtime.h>
#include <hip/hip_bf16.h>

// GRU B=64 T=1024 D=U=512, reset_after=true. fp32 in/out, bf16 MFMA internally.
//
// Phase 2 v13: grouped tagged ring (r14) + issue-early pipeline + single-barrier
// LDS double-buffer + register-pinned weights.
// 64 blocks = 8 batch-groups (gi) x 8 unit-blocks (j). Ring word:
//   u64 {hi32 = step+1, lo32 = bf16(u)|bf16(u+1)<<16}, depth-2 slots.
// Producer: tagged relaxed-agent stores only. Consumer: 8 tagged u64/thread,
// ISSUED AT THE BOTTOM of the previous iteration (validation usually first-try).
// Depth-2 overwrite safety by dataflow induction (r8/r14).
//
// ws layout (bytes):
//   [135168, +262144)        ring u64[8][2][8][256] (overlays dead Wt; memset)
//   [135168, +1572864)       Wt  bf16 [1536][512]  (dead after xm_gemm)
//   [1708032, +1572864)      Rt  bf16 [1536][512]
//   [3280896, +201326592)    XM  bf16 [T*64][1536] (x@W + b_i), row = t*64+b

typedef __attribute__((ext_vector_type(8))) short short8;
typedef __attribute__((ext_vector_type(4))) float f32x4;
typedef __attribute__((ext_vector_type(4))) unsigned int u32x4;

__device__ __forceinline__ unsigned short f2bf(float f) {
  unsigned u = __float_as_uint(f);
  u += 0x7FFFu + ((u >> 16) & 1u);   // RNE
  return (unsigned short)(u >> 16);
}
__device__ __forceinline__ float bf2f(unsigned short s) {
  return __uint_as_float(((unsigned)s) << 16);
}

// ---------------- Phase 0: transpose fp32 [R][C] -> bf16 [C][R] ----------------
__global__ void transpose_cast(const float* __restrict__ src,
                               unsigned short* __restrict__ dst,
                               int R, int C) {
  __shared__ float tile[32][33];
  int c0 = blockIdx.x * 32, r0 = blockIdx.y * 32;
  int tx = threadIdx.x, ty = threadIdx.y;
#pragma unroll
  for (int i = 0; i < 4; i++) {
    tile[ty + i * 8][tx] = src[(size_t)(r0 + ty + i * 8) * C + c0 + tx];
  }
  __syncthreads();
#pragma unroll
  for (int i = 0; i < 4; i++) {
    dst[(size_t)(c0 + ty + i * 8) * R + r0 + tx] = f2bf(tile[tx][ty + i * 8]);
  }
}

// ---------------- Phase 1: XM = x @ W + b_i  (bf16 out) ----------------
__global__ __launch_bounds__(256) void xm_gemm(const float* __restrict__ x,
                                               const unsigned short* __restrict__ Wt,
                                               const float* __restrict__ bias,
                                               unsigned short* __restrict__ XM) {
  __shared__ unsigned short As[128][72];
  __shared__ unsigned short Bs[128][72];
  const int tid = threadIdx.x;
  const int bm = blockIdx.x;   // 512
  const int bn = blockIdx.y;   // 12
  const int wave = tid >> 6, lane = tid & 63;
  const int moff = (wave & 1) * 64, noff = (wave >> 1) * 64;

  f32x4 acc[4][4];
#pragma unroll
  for (int mt = 0; mt < 4; mt++)
#pragma unroll
    for (int nt = 0; nt < 4; nt++) acc[mt][nt] = (f32x4){0.f, 0.f, 0.f, 0.f};

  const int r = tid >> 1;
  const int kb = (tid & 1) * 32;
  const int rg = bm * 128 + r;
  const int bb = rg & 63, tt = rg >> 6;

  for (int k0 = 0; k0 < 512; k0 += 64) {
    const f32x4* xp4 = (const f32x4*)(x + ((size_t)bb * 1024 + tt) * 512 + k0 + kb);
#pragma unroll
    for (int j = 0; j < 4; j++) {
      f32x4 lo = xp4[2 * j];
      f32x4 hi = xp4[2 * j + 1];
      union { unsigned short us[8]; short8 v; } u;
      u.us[0] = f2bf(lo[0]); u.us[1] = f2bf(lo[1]); u.us[2] = f2bf(lo[2]); u.us[3] = f2bf(lo[3]);
      u.us[4] = f2bf(hi[0]); u.us[5] = f2bf(hi[1]); u.us[6] = f2bf(hi[2]); u.us[7] = f2bf(hi[3]);
      *(short8*)&As[r][kb + j * 8] = u.v;
    }
    const short8* wp8 = (const short8*)(Wt + (size_t)(bn * 128 + r) * 512 + k0 + kb);
#pragma unroll
    for (int j = 0; j < 4; j++) *(short8*)&Bs[r][kb + j * 8] = wp8[j];
    __syncthreads();

#pragma unroll
    for (int kk = 0; kk < 2; kk++) {
      short8 a[4], b[4];
#pragma unroll
      for (int mt = 0; mt < 4; mt++)
        a[mt] = *(const short8*)&As[moff + mt * 16 + (lane & 15)][kk * 32 + (lane >> 4) * 8];
#pragma unroll
      for (int nt = 0; nt < 4; nt++)
        b[nt] = *(const short8*)&Bs[noff + nt * 16 + (lane & 15)][kk * 32 + (lane >> 4) * 8];
#pragma unroll
      for (int mt = 0; mt < 4; mt++)
#pragma unroll
        for (int nt = 0; nt < 4; nt++)
          acc[mt][nt] = __builtin_amdgcn_mfma_f32_16x16x32_bf16(a[mt], b[nt], acc[mt][nt], 0, 0, 0);
    }
    __syncthreads();
  }

#pragma unroll
  for (int nt = 0; nt < 4; nt++) {
    const int cg = bn * 128 + noff + nt * 16 + (lane & 15);
    const float bi = bias[cg];
#pragma unroll
    for (int mt = 0; mt < 4; mt++) {
      const int rg2 = bm * 128 + moff + mt * 16 + (lane >> 4) * 4;
#pragma unroll
      for (int i = 0; i < 4; i++)
        XM[(size_t)(rg2 + i) * 1536 + cg] = f2bf(acc[mt][nt][i] + bi);
    }
  }
}

// ---------------- Phase 2: recurrence, pipelined tagged ring ----------------
__global__ __launch_bounds__(256, 1) void gru_rec(const unsigned short* __restrict__ Rt,
                                                  const unsigned short* __restrict__ XM,
                                                  const float* __restrict__ bias,
                                                  unsigned long long* ring,
                                                  float* __restrict__ out) {
  const int tid = threadIdx.x;
  const int lane = tid & 63;
  const int w = tid >> 6;             // wave 0..3
  const int blk = blockIdx.x;         // 0..63
  const int gi = blk >> 3;            // batch group: batches [8gi, +8)
  const int j = blk & 7;              // unit block:  units   [64j, +64)
  const int u0 = j * 64 + w * 16;     // this wave's 16-unit slice
  const int col = lane & 15;
  const int krow = lane >> 4;         // 0..3
  const int hrow = col & 7;           // LDS h row this lane's A-frag reads

  unsigned long long* ring_g = ring + (size_t)gi * 4096;   // u64[2][8][256]

  __shared__ alignas(16) unsigned short hlds[2][8][512];   // double-buffered

  // weights: plain loads, then pinned live via per-iteration empty asm
  short8 Bf[3][16];
#pragma unroll
  for (int g3 = 0; g3 < 3; g3++)
#pragma unroll
    for (int ks = 0; ks < 16; ks++)
      Bf[g3][ks] = *(const short8*)(Rt + (size_t)(g3 * 512 + u0 + col) * 512 + ks * 32 + krow * 8);

  const float br0 = bias[1536 + 0 * 512 + u0 + col];
  const float br1 = bias[1536 + 1 * 512 + u0 + col];
  const float br2 = bias[1536 + 2 * 512 + u0 + col];

  float hreg[4] = {0.f, 0.f, 0.f, 0.f};

  // coop staging chunks: c1 = tid (rows 0..3), c2 = tid+256 (rows 4..7)
  const int c1 = tid, c2 = tid + 256;
  const int r1 = c1 >> 6, c1s = (c1 & 63) ^ r1;
  const int r2 = c2 >> 6, c2s = (c2 & 63) ^ r2;

  unsigned short xc[3][4], xn[3][4];
#pragma unroll
  for (int g3 = 0; g3 < 3; g3++)
#pragma unroll
    for (int i = 0; i < 4; i++) {
      int batch = gi * 8 + ((krow * 4 + i) & 7);
      xc[g3][i] = XM[(size_t)batch * 1536 + g3 * 512 + u0 + col];
    }

  unsigned long long q[8];            // in-flight tagged words for next consume

#pragma unroll 1
  for (int t = 0; t < 1024; ++t) {
    f32x4 acc0 = (f32x4){0.f, 0.f, 0.f, 0.f};
    f32x4 acc1 = acc0, acc2 = acc0;

    if (t > 0) {
      const unsigned tagv = (unsigned)t;
      const int ls = (t + 1) & 1;     // ring & LDS slot for this consume
      const unsigned long long* rp = ring_g + (size_t)ls * 2048;
      // ---- validate (loads were issued at the bottom of iteration t-1) ----
      for (;;) {
        unsigned bad = 0;
#pragma unroll
        for (int k = 0; k < 8; ++k) bad |= ((unsigned)(q[k] >> 32)) ^ tagv;
        if (__all((int)(bad == 0))) break;
        __builtin_amdgcn_s_sleep(1);
#pragma unroll
        for (int k = 0; k < 4; ++k) {
          q[k] = __hip_atomic_load(rp + 4 * c1 + k, __ATOMIC_RELAXED,
                                   __HIP_MEMORY_SCOPE_AGENT);
          q[4 + k] = __hip_atomic_load(rp + 4 * c2 + k, __ATOMIC_RELAXED,
                                       __HIP_MEMORY_SCOPE_AGENT);
        }
      }

      // ---- swizzled LDS write (double-buffered; single barrier per step) ----
      *(u32x4*)&hlds[ls][r1][c1s * 8] =
          (u32x4){(unsigned)q[0], (unsigned)q[1], (unsigned)q[2], (unsigned)q[3]};
      *(u32x4*)&hlds[ls][r2][c2s * 8] =
          (u32x4){(unsigned)q[4], (unsigned)q[5], (unsigned)q[6], (unsigned)q[7]};
      __syncthreads();

      // ---- fragments from LDS + MFMA ----
      short8 Af[16];
#pragma unroll
      for (int ks = 0; ks < 16; ++ks)
        Af[ks] = *(const short8*)&hlds[ls][hrow][(((ks << 2) + krow) ^ hrow) * 8];
#pragma unroll
      for (int ks = 0; ks < 16; ++ks) {
        acc0 = __builtin_amdgcn_mfma_f32_16x16x32_bf16(Af[ks], Bf[0][ks], acc0, 0, 0, 0);
        acc1 = __builtin_amdgcn_mfma_f32_16x16x32_bf16(Af[ks], Bf[1][ks], acc1, 0, 0, 0);
        acc2 = __builtin_amdgcn_mfma_f32_16x16x32_bf16(Af[ks], Bf[2][ks], acc2, 0, 0, 0);
      }
    }

    // gates (fp32); identical arithmetic since r2. krow>=2 rows are benign dups.
#pragma unroll
    for (int i = 0; i < 4; i++) {
      float hz = acc0[i] + br0;
      float hr = acc1[i] + br1;
      float hh = acc2[i] + br2;
      float xz = bf2f(xc[0][i]);
      float xr = bf2f(xc[1][i]);
      float xh = bf2f(xc[2][i]);
      float z = 1.f / (1.f + __expf(-(xz + hz)));
      float r = 1.f / (1.f + __expf(-(xr + hr)));
      float y = xh + r * hh;
      float ay = fabsf(y);
      float e = __expf(-2.f * ay);
      float ca = (1.f - e) / (1.f + e);          // |tanh|
      ca = (y < 0.f) ? -ca : ca;
      hreg[i] = z * hreg[i] + (1.f - z) * ca;
    }

    if (t < 1023) {
      // producer: tagged stores only (tag travels with data; depth-2 induction).
      unsigned long long* hw = ring_g + (size_t)(t & 1) * 2048;
      const unsigned long long tagbits = ((unsigned long long)(unsigned)(t + 1)) << 32;
#pragma unroll
      for (int i = 0; i < 4; i++) {
        int lb = krow * 4 + i;              // local batch; valid when krow<2
        float other = __shfl_xor(hreg[i], 1);
        if (krow < 2 && (col & 1) == 0) {
          unsigned d = (unsigned)f2bf(hreg[i]) | ((unsigned)f2bf(other) << 16);
          __hip_atomic_store(hw + (size_t)lb * 256 + ((u0 + col) >> 1),
                             tagbits | (unsigned long long)d,
                             __ATOMIC_RELAXED, __HIP_MEMORY_SCOPE_AGENT);
        }
      }
      // ---- issue-early: loads for step t+1's consume (slot t&1) ----
      const unsigned long long* rp2 = ring_g + (size_t)(t & 1) * 2048;
#pragma unroll
      for (int k = 0; k < 4; ++k) {
        q[k] = __hip_atomic_load(rp2 + 4 * c1 + k, __ATOMIC_RELAXED,
                                 __HIP_MEMORY_SCOPE_AGENT);
        q[4 + k] = __hip_atomic_load(rp2 + 4 * c2 + k, __ATOMIC_RELAXED,
                                     __HIP_MEMORY_SCOPE_AGENT);
      }
    }

    // XM prefetch for t+1 (overlaps the in-flight ring loads)
    const int tn = (t < 1023) ? t + 1 : 1023;
#pragma unroll
    for (int g3 = 0; g3 < 3; g3++)
#pragma unroll
      for (int i = 0; i < 4; i++) {
        int batch = gi * 8 + ((krow * 4 + i) & 7);
        xn[g3][i] = XM[(size_t)(tn * 64 + batch) * 1536 + g3 * 512 + u0 + col];
      }
#pragma unroll
    for (int g3 = 0; g3 < 3; g3++)
#pragma unroll
      for (int i = 0; i < 4; i++) xc[g3][i] = xn[g3][i];

    // pin weights live across the loop (no instruction emitted; blocks remat)
#pragma unroll
    for (int g3 = 0; g3 < 3; g3++)
#pragma unroll
      for (int ks = 0; ks < 16; ks++)
        asm volatile("" : "+v"(Bf[g3][ks]));
  }

  if (krow < 2) {
#pragma unroll
    for (int i = 0; i < 4; i++)
      out[(size_t)(gi * 8 + krow * 4 + i) * 512 + u0 + col] = hreg[i];
  }
}

// ---------------- launch ----------------
extern "C" void kernel_launch(void* const* d_in, const int* in_sizes, int n_in,
                              void* d_out, int out_size, void* d_ws, size_t ws_size,
                              hipStream_t stream) {
  const float* x = (const float*)d_in[0];       // [64][1024][512]
  const float* W = (const float*)d_in[1];       // [512][1536]
  const float* R = (const float*)d_in[2];       // [512][1536]
  const float* bias = (const float*)d_in[3];    // [2][1536]
  float* out = (float*)d_out;

  char* ws = (char*)d_ws;
  unsigned short* Wt = (unsigned short*)(ws + 135168);
  unsigned long long* ring = (unsigned long long*)(ws + 135168);  // overlays Wt
  unsigned short* Rt = (unsigned short*)(ws + 1708032);
  unsigned short* XM = (unsigned short*)(ws + 3280896);

  transpose_cast<<<dim3(48, 16), dim3(32, 8), 0, stream>>>(W, Wt, 512, 1536);
  transpose_cast<<<dim3(48, 16), dim3(32, 8), 0, stream>>>(R, Rt, 512, 1536);
  xm_gemm<<<dim3(512, 12), dim3(256), 0, stream>>>(x, Wt, bias, XM);
  // Wt dead now; zero the tagged ring (tag 0 matches no step t in [1,1024]).
  hipMemsetAsync(ring, 0, 8ull * 2 * 8 * 256 * 8, stream);
  gru_rec<<<dim3(64), dim3(256), 0, stream>>>(Rt, XM, bias, ring, out);
}

// Round 16
// 2964.125 us; speedup vs baseline: 1.4414x; 1.4414x over previous
//
#include <hip/hip_runtime.h>
#include <hip/hip_bf16.h>

// GRU B=64 T=1024 D=U=512, reset_after=true. fp32 in/out, bf16 MFMA internally.
//
// Phase 2 v14: r14's grouped tagged ring (proven 2.59us/step) +
//   - single-barrier LDS double-buffer (r15, parity-proven safe)
//   - per-lane conditional reload on retry (cuts straggler traffic ~8x)
//   - loads issued AT consume time (r14 timing; r15's issue-early regressed)
// 64 blocks = 8 batch-groups (gi) x 8 unit-blocks (j). Ring word:
//   u64 {hi32 = step+1, lo32 = bf16(u)|bf16(u+1)<<16}, depth-2 slots.
// Producer: tagged relaxed-agent stores only. Depth-2 overwrite safety by
// dataflow induction (r8/r14).
//
// ws layout (bytes):
//   [135168, +262144)        ring u64[8][2][8][256] (overlays dead Wt; memset)
//   [135168, +1572864)       Wt  bf16 [1536][512]  (dead after xm_gemm)
//   [1708032, +1572864)      Rt  bf16 [1536][512]
//   [3280896, +201326592)    XM  bf16 [T*64][1536] (x@W + b_i), row = t*64+b

typedef __attribute__((ext_vector_type(8))) short short8;
typedef __attribute__((ext_vector_type(4))) float f32x4;
typedef __attribute__((ext_vector_type(4))) unsigned int u32x4;

__device__ __forceinline__ unsigned short f2bf(float f) {
  unsigned u = __float_as_uint(f);
  u += 0x7FFFu + ((u >> 16) & 1u);   // RNE
  return (unsigned short)(u >> 16);
}
__device__ __forceinline__ float bf2f(unsigned short s) {
  return __uint_as_float(((unsigned)s) << 16);
}

// ---------------- Phase 0: transpose fp32 [R][C] -> bf16 [C][R] ----------------
__global__ void transpose_cast(const float* __restrict__ src,
                               unsigned short* __restrict__ dst,
                               int R, int C) {
  __shared__ float tile[32][33];
  int c0 = blockIdx.x * 32, r0 = blockIdx.y * 32;
  int tx = threadIdx.x, ty = threadIdx.y;
#pragma unroll
  for (int i = 0; i < 4; i++) {
    tile[ty + i * 8][tx] = src[(size_t)(r0 + ty + i * 8) * C + c0 + tx];
  }
  __syncthreads();
#pragma unroll
  for (int i = 0; i < 4; i++) {
    dst[(size_t)(c0 + ty + i * 8) * R + r0 + tx] = f2bf(tile[tx][ty + i * 8]);
  }
}

// ---------------- Phase 1: XM = x @ W + b_i  (bf16 out) ----------------
__global__ __launch_bounds__(256) void xm_gemm(const float* __restrict__ x,
                                               const unsigned short* __restrict__ Wt,
                                               const float* __restrict__ bias,
                                               unsigned short* __restrict__ XM) {
  __shared__ unsigned short As[128][72];
  __shared__ unsigned short Bs[128][72];
  const int tid = threadIdx.x;
  const int bm = blockIdx.x;   // 512
  const int bn = blockIdx.y;   // 12
  const int wave = tid >> 6, lane = tid & 63;
  const int moff = (wave & 1) * 64, noff = (wave >> 1) * 64;

  f32x4 acc[4][4];
#pragma unroll
  for (int mt = 0; mt < 4; mt++)
#pragma unroll
    for (int nt = 0; nt < 4; nt++) acc[mt][nt] = (f32x4){0.f, 0.f, 0.f, 0.f};

  const int r = tid >> 1;
  const int kb = (tid & 1) * 32;
  const int rg = bm * 128 + r;
  const int bb = rg & 63, tt = rg >> 6;

  for (int k0 = 0; k0 < 512; k0 += 64) {
    const f32x4* xp4 = (const f32x4*)(x + ((size_t)bb * 1024 + tt) * 512 + k0 + kb);
#pragma unroll
    for (int j = 0; j < 4; j++) {
      f32x4 lo = xp4[2 * j];
      f32x4 hi = xp4[2 * j + 1];
      union { unsigned short us[8]; short8 v; } u;
      u.us[0] = f2bf(lo[0]); u.us[1] = f2bf(lo[1]); u.us[2] = f2bf(lo[2]); u.us[3] = f2bf(lo[3]);
      u.us[4] = f2bf(hi[0]); u.us[5] = f2bf(hi[1]); u.us[6] = f2bf(hi[2]); u.us[7] = f2bf(hi[3]);
      *(short8*)&As[r][kb + j * 8] = u.v;
    }
    const short8* wp8 = (const short8*)(Wt + (size_t)(bn * 128 + r) * 512 + k0 + kb);
#pragma unroll
    for (int j = 0; j < 4; j++) *(short8*)&Bs[r][kb + j * 8] = wp8[j];
    __syncthreads();

#pragma unroll
    for (int kk = 0; kk < 2; kk++) {
      short8 a[4], b[4];
#pragma unroll
      for (int mt = 0; mt < 4; mt++)
        a[mt] = *(const short8*)&As[moff + mt * 16 + (lane & 15)][kk * 32 + (lane >> 4) * 8];
#pragma unroll
      for (int nt = 0; nt < 4; nt++)
        b[nt] = *(const short8*)&Bs[noff + nt * 16 + (lane & 15)][kk * 32 + (lane >> 4) * 8];
#pragma unroll
      for (int mt = 0; mt < 4; mt++)
#pragma unroll
        for (int nt = 0; nt < 4; nt++)
          acc[mt][nt] = __builtin_amdgcn_mfma_f32_16x16x32_bf16(a[mt], b[nt], acc[mt][nt], 0, 0, 0);
    }
    __syncthreads();
  }

#pragma unroll
  for (int nt = 0; nt < 4; nt++) {
    const int cg = bn * 128 + noff + nt * 16 + (lane & 15);
    const float bi = bias[cg];
#pragma unroll
    for (int mt = 0; mt < 4; mt++) {
      const int rg2 = bm * 128 + moff + mt * 16 + (lane >> 4) * 4;
#pragma unroll
      for (int i = 0; i < 4; i++)
        XM[(size_t)(rg2 + i) * 1536 + cg] = f2bf(acc[mt][nt][i] + bi);
    }
  }
}

// ---------------- Phase 2: recurrence, grouped tagged ring (r14 timing) ----------------
__global__ __launch_bounds__(256, 1) void gru_rec(const unsigned short* __restrict__ Rt,
                                                  const unsigned short* __restrict__ XM,
                                                  const float* __restrict__ bias,
                                                  unsigned long long* ring,
                                                  float* __restrict__ out) {
  const int tid = threadIdx.x;
  const int lane = tid & 63;
  const int w = tid >> 6;             // wave 0..3
  const int blk = blockIdx.x;         // 0..63
  const int gi = blk >> 3;            // batch group: batches [8gi, +8)
  const int j = blk & 7;              // unit block:  units   [64j, +64)
  const int u0 = j * 64 + w * 16;     // this wave's 16-unit slice
  const int col = lane & 15;
  const int krow = lane >> 4;         // 0..3
  const int hrow = col & 7;           // LDS h row this lane's A-frag reads

  unsigned long long* ring_g = ring + (size_t)gi * 4096;   // u64[2][8][256]

  __shared__ alignas(16) unsigned short hlds[2][8][512];   // double-buffered

  // weights: plain loads, compiler-managed (r11/r13/r14-proven)
  short8 Bf[3][16];
#pragma unroll
  for (int g3 = 0; g3 < 3; g3++)
#pragma unroll
    for (int ks = 0; ks < 16; ks++)
      Bf[g3][ks] = *(const short8*)(Rt + (size_t)(g3 * 512 + u0 + col) * 512 + ks * 32 + krow * 8);

  const float br0 = bias[1536 + 0 * 512 + u0 + col];
  const float br1 = bias[1536 + 1 * 512 + u0 + col];
  const float br2 = bias[1536 + 2 * 512 + u0 + col];

  float hreg[4] = {0.f, 0.f, 0.f, 0.f};

  // coop staging chunks: c1 = tid (rows 0..3), c2 = tid+256 (rows 4..7)
  const int c1 = tid, c2 = tid + 256;
  const int r1 = c1 >> 6, c1s = (c1 & 63) ^ r1;
  const int r2 = c2 >> 6, c2s = (c2 & 63) ^ r2;

  unsigned short xc[3][4], xn[3][4];
#pragma unroll
  for (int g3 = 0; g3 < 3; g3++)
#pragma unroll
    for (int i = 0; i < 4; i++) {
      int batch = gi * 8 + ((krow * 4 + i) & 7);
      xc[g3][i] = XM[(size_t)batch * 1536 + g3 * 512 + u0 + col];
    }

#pragma unroll 1
  for (int t = 0; t < 1024; ++t) {
    f32x4 acc0 = (f32x4){0.f, 0.f, 0.f, 0.f};
    f32x4 acc1 = acc0, acc2 = acc0;

    if (t > 0) {
      // ---- tagged slice load at consume time (r14 timing) ----
      const unsigned tagv = (unsigned)t;
      const int ls = (t + 1) & 1;     // ring & LDS slot for this consume
      const unsigned long long* rp = ring_g + (size_t)ls * 2048;
      unsigned long long q[8];
      unsigned bad;
      {
        bad = 0;
#pragma unroll
        for (int k = 0; k < 4; ++k) {
          q[k] = __hip_atomic_load(rp + 4 * c1 + k, __ATOMIC_RELAXED,
                                   __HIP_MEMORY_SCOPE_AGENT);
          q[4 + k] = __hip_atomic_load(rp + 4 * c2 + k, __ATOMIC_RELAXED,
                                       __HIP_MEMORY_SCOPE_AGENT);
        }
#pragma unroll
        for (int k = 0; k < 8; ++k) bad |= ((unsigned)(q[k] >> 32)) ^ tagv;
      }
      while (!__all((int)(bad == 0))) {
        __builtin_amdgcn_s_sleep(1);
        if (bad) {                     // only straggler lanes reload
          bad = 0;
#pragma unroll
          for (int k = 0; k < 4; ++k) {
            q[k] = __hip_atomic_load(rp + 4 * c1 + k, __ATOMIC_RELAXED,
                                     __HIP_MEMORY_SCOPE_AGENT);
            q[4 + k] = __hip_atomic_load(rp + 4 * c2 + k, __ATOMIC_RELAXED,
                                         __HIP_MEMORY_SCOPE_AGENT);
          }
#pragma unroll
          for (int k = 0; k < 8; ++k) bad |= ((unsigned)(q[k] >> 32)) ^ tagv;
        }
      }

      // ---- swizzled LDS write (double-buffered; single barrier per step) ----
      *(u32x4*)&hlds[ls][r1][c1s * 8] =
          (u32x4){(unsigned)q[0], (unsigned)q[1], (unsigned)q[2], (unsigned)q[3]};
      *(u32x4*)&hlds[ls][r2][c2s * 8] =
          (u32x4){(unsigned)q[4], (unsigned)q[5], (unsigned)q[6], (unsigned)q[7]};
      __syncthreads();

      // ---- fragments from LDS + MFMA ----
      short8 Af[16];
#pragma unroll
      for (int ks = 0; ks < 16; ++ks)
        Af[ks] = *(const short8*)&hlds[ls][hrow][(((ks << 2) + krow) ^ hrow) * 8];
#pragma unroll
      for (int ks = 0; ks < 16; ++ks) {
        acc0 = __builtin_amdgcn_mfma_f32_16x16x32_bf16(Af[ks], Bf[0][ks], acc0, 0, 0, 0);
        acc1 = __builtin_amdgcn_mfma_f32_16x16x32_bf16(Af[ks], Bf[1][ks], acc1, 0, 0, 0);
        acc2 = __builtin_amdgcn_mfma_f32_16x16x32_bf16(Af[ks], Bf[2][ks], acc2, 0, 0, 0);
      }
    }

    // gates (fp32); identical arithmetic since r2. krow>=2 rows are benign dups.
#pragma unroll
    for (int i = 0; i < 4; i++) {
      float hz = acc0[i] + br0;
      float hr = acc1[i] + br1;
      float hh = acc2[i] + br2;
      float xz = bf2f(xc[0][i]);
      float xr = bf2f(xc[1][i]);
      float xh = bf2f(xc[2][i]);
      float z = 1.f / (1.f + __expf(-(xz + hz)));
      float r = 1.f / (1.f + __expf(-(xr + hr)));
      float y = xh + r * hh;
      float ay = fabsf(y);
      float e = __expf(-2.f * ay);
      float ca = (1.f - e) / (1.f + e);          // |tanh|
      ca = (y < 0.f) ? -ca : ca;
      hreg[i] = z * hreg[i] + (1.f - z) * ca;
    }

    if (t < 1023) {
      // producer: tagged stores only (tag travels with data; depth-2 induction).
      unsigned long long* hw = ring_g + (size_t)(t & 1) * 2048;
      const unsigned long long tagbits = ((unsigned long long)(unsigned)(t + 1)) << 32;
#pragma unroll
      for (int i = 0; i < 4; i++) {
        int lb = krow * 4 + i;              // local batch; valid when krow<2
        float other = __shfl_xor(hreg[i], 1);
        if (krow < 2 && (col & 1) == 0) {
          unsigned d = (unsigned)f2bf(hreg[i]) | ((unsigned)f2bf(other) << 16);
          __hip_atomic_store(hw + (size_t)lb * 256 + ((u0 + col) >> 1),
                             tagbits | (unsigned long long)d,
                             __ATOMIC_RELAXED, __HIP_MEMORY_SCOPE_AGENT);
        }
      }
    }

    // XM prefetch for t+1 (off the critical store path)
    const int tn = (t < 1023) ? t + 1 : 1023;
#pragma unroll
    for (int g3 = 0; g3 < 3; g3++)
#pragma unroll
      for (int i = 0; i < 4; i++) {
        int batch = gi * 8 + ((krow * 4 + i) & 7);
        xn[g3][i] = XM[(size_t)(tn * 64 + batch) * 1536 + g3 * 512 + u0 + col];
      }
#pragma unroll
    for (int g3 = 0; g3 < 3; g3++)
#pragma unroll
      for (int i = 0; i < 4; i++) xc[g3][i] = xn[g3][i];
  }

  if (krow < 2) {
#pragma unroll
    for (int i = 0; i < 4; i++)
      out[(size_t)(gi * 8 + krow * 4 + i) * 512 + u0 + col] = hreg[i];
  }
}

// ---------------- launch ----------------
extern "C" void kernel_launch(void* const* d_in, const int* in_sizes, int n_in,
                              void* d_out, int out_size, void* d_ws, size_t ws_size,
                              hipStream_t stream) {
  const float* x = (const float*)d_in[0];       // [64][1024][512]
  const float* W = (const float*)d_in[1];       // [512][1536]
  const float* R = (const float*)d_in[2];       // [512][1536]
  const float* bias = (const float*)d_in[3];    // [2][1536]
  float* out = (float*)d_out;

  char* ws = (char*)d_ws;
  unsigned short* Wt = (unsigned short*)(ws + 135168);
  unsigned long long* ring = (unsigned long long*)(ws + 135168);  // overlays Wt
  unsigned short* Rt = (unsigned short*)(ws + 1708032);
  unsigned short* XM = (unsigned short*)(ws + 3280896);

  transpose_cast<<<dim3(48, 16), dim3(32, 8), 0, stream>>>(W, Wt, 512, 1536);
  transpose_cast<<<dim3(48, 16), dim3(32, 8), 0, stream>>>(R, Rt, 512, 1536);
  xm_gemm<<<dim3(512, 12), dim3(256), 0, stream>>>(x, Wt, bias, XM);
  // Wt dead now; zero the tagged ring (tag 0 matches no step t in [1,1024]).
  hipMemsetAsync(ring, 0, 8ull * 2 * 8 * 256 * 8, stream);
  gru_rec<<<dim3(64), dim3(256), 0, stream>>>(Rt, XM, bias, ring, out);
}